// Round 7
// baseline (1407.247 us; speedup 1.0000x reference)
//
#include <hip/hip_runtime.h>

#define THREADS 256
#define NPB 128            // nodes per bucket (power of 2)
#define NPB_SHIFT 7
#define MAXB 1024          // max buckets supported (N <= 131072)
#define EPB 4096           // edges per binsort block
#define EPT 16             // edges per thread (EPB = THREADS*EPT)

// ---------------- bucket histogram ----------------

__global__ __launch_bounds__(THREADS) void k_bcount(const int* __restrict__ tgt,
                                                    int* __restrict__ bcnt,
                                                    int E, int NBUK) {
    __shared__ int h[MAXB];
    for (int t = threadIdx.x; t < NBUK; t += THREADS) h[t] = 0;
    __syncthreads();
    int base = blockIdx.x * EPB + threadIdx.x;
    #pragma unroll
    for (int k = 0; k < EPT; ++k) {
        int e = base + k * THREADS;
        if (e < E) atomicAdd(&h[tgt[e] >> NPB_SHIFT], 1);
    }
    __syncthreads();
    for (int t = threadIdx.x; t < NBUK; t += THREADS)
        if (h[t]) atomicAdd(&bcnt[t], h[t]);
}

// ---------------- single-block scan of bucket sizes ----------------

__global__ __launch_bounds__(1024) void k_bscan(const int* __restrict__ bcnt,
                                                int* __restrict__ bbase,
                                                int* __restrict__ bcursor,
                                                int NBUK, int E) {
    __shared__ int lds[1024];
    int t = threadIdx.x;
    int v = (t < NBUK) ? bcnt[t] : 0;
    lds[t] = v; __syncthreads();
    for (int off = 1; off < 1024; off <<= 1) {
        int x = (t >= off) ? lds[t - off] : 0;
        __syncthreads();
        lds[t] += x;
        __syncthreads();
    }
    if (t < NBUK) { int ex = lds[t] - v; bbase[t] = ex; bcursor[t] = ex; }
    if (t == 0) bbase[NBUK] = E;
}

// ---------------- binsort: clustered payload scatter ----------------
// payload row (16 floats = 64B): [s,u0,u1,u2 | q0,q1,q2,q3 | q4,src,tgt,0 | 0,0,0,0]

__global__ __launch_bounds__(THREADS) void k_binsort(const int* __restrict__ eidx,
                                                     int* __restrict__ bcursor,
                                                     const float* __restrict__ sh0,
                                                     const float* __restrict__ sh1,
                                                     const float* __restrict__ sh2,
                                                     float* __restrict__ payload,
                                                     int E, int NBUK) {
    __shared__ int h[MAXB];
    for (int t = threadIdx.x; t < NBUK; t += THREADS) h[t] = 0;
    __syncthreads();

    int base = blockIdx.x * EPB + threadIdx.x;
    int myb[EPT];
    #pragma unroll
    for (int k = 0; k < EPT; ++k) {
        int e = base + k * THREADS;
        myb[k] = 0;
        if (e < E) { int b = eidx[E + e] >> NPB_SHIFT; myb[k] = b; atomicAdd(&h[b], 1); }
    }
    __syncthreads();

    // reserve a contiguous chunk per bucket for this block
    for (int t = threadIdx.x; t < NBUK; t += THREADS) {
        int c = h[t];
        h[t] = c ? atomicAdd(&bcursor[t], c) : 0;   // h now holds running slot
    }
    __syncthreads();

    #pragma unroll
    for (int k = 0; k < EPT; ++k) {
        int e = base + k * THREADS;
        if (e >= E) continue;
        int slot = atomicAdd(&h[myb[k]], 1);        // consecutive slots per bucket
        int src = eidx[e];
        int tg  = eidx[E + e];
        float4 p0 = make_float4(sh0[e], sh1[3*e+0], sh1[3*e+1], sh1[3*e+2]);
        float4 p1 = make_float4(sh2[5*e+0], sh2[5*e+1], sh2[5*e+2], sh2[5*e+3]);
        float4 p2 = make_float4(sh2[5*e+4], __int_as_float(src), __int_as_float(tg), 0.f);
        float4 p3 = make_float4(0.f, 0.f, 0.f, 0.f);
        float4* pr = (float4*)(payload + (size_t)slot * 16);
        pr[0] = p0; pr[1] = p1; pr[2] = p2; pr[3] = p3;   // full 64B
    }
}

// ---------------- per-bucket aggregation with LDS accumulators ----------------
// one block per bucket; 8 threads per edge (channel i); acc[128 nodes][8ch][14]

#define ACCS 113   // 112 + 1 pad

__global__ __launch_bounds__(THREADS) void k_aggb(const float* __restrict__ node,
                                                  const float* __restrict__ payload,
                                                  const int*   __restrict__ bbase,
                                                  const float* __restrict__ W,
                                                  float*       __restrict__ out, int N) {
    __shared__ float sW[384];
    __shared__ float acc[NPB * ACCS];
    for (int t = threadIdx.x; t < 384; t += THREADS) sW[t] = W[t];
    for (int t = threadIdx.x; t < NPB * ACCS; t += THREADS) acc[t] = 0.f;
    __syncthreads();

    constexpr float IS3  = 0.57735026918962576f;
    constexpr float IS6  = 0.40824829046386302f;
    constexpr float IS10 = 0.31622776601683794f;
    constexpr float IS30 = 0.18257418583505536f;

    const int b = blockIdx.x;
    const int jbeg = bbase[b], jend = bbase[b + 1];
    const int g = threadIdx.x >> 3;      // 32 edge-groups per block
    const int i = threadIdx.x & 7;       // input channel
    const int nbase = b << NPB_SHIFT;

    for (int j = jbeg + g; j < jend; j += 32) {
        const float* pr = payload + (size_t)j * 16;
        const float s  = pr[0], u0 = pr[1], u1 = pr[2], u2 = pr[3];
        const float q0 = pr[4], q1 = pr[5], q2 = pr[6], q3 = pr[7], q4 = pr[8];
        const int src = __float_as_int(pr[9]);
        const int nl  = __float_as_int(pr[10]) - nbase;

        const float* nr = node + (size_t)src * 32;
        const float f0 = nr[i];
        const float x  = nr[8 + 3*i + 0];
        const float y  = nr[8 + 3*i + 1];
        const float z  = nr[8 + 3*i + 2];

        const float Q00 = -q2*IS30 - q4*IS10;
        const float Q01 =  q1*IS10;
        const float Q02 =  q0*IS10;
        const float Q11 =  2.0f*q2*IS30;
        const float Q12 =  q3*IS10;
        const float Q22 = -q2*IS30 + q4*IS10;

        float* A = &acc[nl * ACCS + i * 14];
        atomicAdd(&A[0],  s * f0);
        atomicAdd(&A[1],  u0*x + u1*y + u2*z);
        atomicAdd(&A[2],  s * x);
        atomicAdd(&A[3],  s * y);
        atomicAdd(&A[4],  s * z);
        atomicAdd(&A[5],  f0 * u0);
        atomicAdd(&A[6],  f0 * u1);
        atomicAdd(&A[7],  f0 * u2);
        atomicAdd(&A[8],  u1*z - u2*y);
        atomicAdd(&A[9],  u2*x - u0*z);
        atomicAdd(&A[10], u0*y - u1*x);
        atomicAdd(&A[11], Q00*x + Q01*y + Q02*z);
        atomicAdd(&A[12], Q01*x + Q11*y + Q12*z);
        atomicAdd(&A[13], Q02*x + Q12*y + Q22*z);
    }
    __syncthreads();

    // postmix: one (node, out-channel) pair per thread, looped
    for (int r = threadIdx.x; r < NPB * 8; r += THREADS) {
        const int ns = r >> 3, o = r & 7;
        const int n = nbase + ns;
        if (n >= N) continue;
        float o0 = 0.f, ox = 0.f, oy = 0.f, oz = 0.f;
        #pragma unroll
        for (int ii = 0; ii < 8; ++ii) {
            const float* A = &acc[ns * ACCS + ii * 14];
            const float w0 = sW[      ii*8 + o];
            const float w1 = sW[ 64 + ii*8 + o] * IS3;
            const float w2 = sW[128 + ii*8 + o] * IS3;
            const float w3 = sW[192 + ii*8 + o] * IS3;
            const float w4 = sW[256 + ii*8 + o] * IS6;
            const float w5 = sW[320 + ii*8 + o];
            o0 += w0*A[0]  + w3*A[1];
            ox += w1*A[2]  + w2*A[5] + w4*A[8]  + w5*A[11];
            oy += w1*A[3]  + w2*A[6] + w4*A[9]  + w5*A[12];
            oz += w1*A[4]  + w2*A[7] + w4*A[10] + w5*A[13];
        }
        float* orow = out + (size_t)n * 32;
        orow[o]           = o0;
        orow[8 + 3*o + 0] = ox;
        orow[8 + 3*o + 1] = oy;
        orow[8 + 3*o + 2] = oz;
    }
}

// ---------------- fallback: round-1 atomic kernel ----------------

__global__ __launch_bounds__(THREADS) void msg_kernel_atomic(
    const float* __restrict__ node,
    const int*   __restrict__ eidx,
    const float* __restrict__ sh0,
    const float* __restrict__ sh1,
    const float* __restrict__ sh2,
    const float* __restrict__ W,
    float*       __restrict__ out,
    int E)
{
    __shared__ float sW[384];
    for (int t = threadIdx.x; t < 384; t += THREADS) sW[t] = W[t];
    __syncthreads();

    int e = blockIdx.x * THREADS + threadIdx.x;
    if (e >= E) return;

    constexpr float IS3  = 0.57735026918962576f;
    constexpr float IS6  = 0.40824829046386302f;
    constexpr float IS10 = 0.31622776601683794f;
    constexpr float IS30 = 0.18257418583505536f;

    const int src = eidx[e];
    const int tgt = eidx[E + e];

    const float s  = sh0[e];
    const float u0 = sh1[3*e+0], u1 = sh1[3*e+1], u2 = sh1[3*e+2];
    const float q0 = sh2[5*e+0], q1 = sh2[5*e+1], q2 = sh2[5*e+2],
                q3 = sh2[5*e+3], q4 = sh2[5*e+4];

    const float Q00 = -q2*IS30 - q4*IS10;
    const float Q01 =  q1*IS10;
    const float Q02 =  q0*IS10;
    const float Q11 =  2.0f*q2*IS30;
    const float Q12 =  q3*IS10;
    const float Q22 = -q2*IS30 + q4*IS10;

    float f[32];
    {
        const float4* nr = (const float4*)(node + (size_t)src * 32);
        #pragma unroll
        for (int i = 0; i < 8; ++i) {
            float4 v = nr[i];
            f[4*i+0]=v.x; f[4*i+1]=v.y; f[4*i+2]=v.z; f[4*i+3]=v.w;
        }
    }

    float msg[32];
    #pragma unroll
    for (int j = 0; j < 32; ++j) msg[j] = 0.0f;

    const float s13 = s * IS3;

    #pragma unroll
    for (int i = 0; i < 8; ++i) {
        const float f0i = f[i];
        const float x = f[8+3*i+0], y = f[8+3*i+1], z = f[8+3*i+2];
        const float c0  = s * f0i;
        const float c3  = IS3 * (u0*x + u1*y + u2*z);
        const float p2  = IS3 * f0i;
        const float c1x = s13*x, c1y = s13*y, c1z = s13*z;
        const float c2x = p2*u0, c2y = p2*u1, c2z = p2*u2;
        const float c4x = IS6*(u1*z - u2*y);
        const float c4y = IS6*(u2*x - u0*z);
        const float c4z = IS6*(u0*y - u1*x);
        const float c5x = Q00*x + Q01*y + Q02*z;
        const float c5y = Q01*x + Q11*y + Q12*z;
        const float c5z = Q02*x + Q12*y + Q22*z;

        float wr[6][8];
        #pragma unroll
        for (int c = 0; c < 6; ++c) {
            float4 aa = *(const float4*)&sW[c*64 + i*8 + 0];
            float4 bb = *(const float4*)&sW[c*64 + i*8 + 4];
            wr[c][0]=aa.x; wr[c][1]=aa.y; wr[c][2]=aa.z; wr[c][3]=aa.w;
            wr[c][4]=bb.x; wr[c][5]=bb.y; wr[c][6]=bb.z; wr[c][7]=bb.w;
        }

        #pragma unroll
        for (int o = 0; o < 8; ++o) {
            msg[o] += wr[0][o]*c0 + wr[3][o]*c3;
            msg[8+3*o+0] += wr[1][o]*c1x + wr[2][o]*c2x + wr[4][o]*c4x + wr[5][o]*c5x;
            msg[8+3*o+1] += wr[1][o]*c1y + wr[2][o]*c2y + wr[4][o]*c4y + wr[5][o]*c5y;
            msg[8+3*o+2] += wr[1][o]*c1z + wr[2][o]*c2z + wr[4][o]*c4z + wr[5][o]*c5z;
        }
    }

    float* orow = out + (size_t)tgt * 32;
    #pragma unroll
    for (int j = 0; j < 32; ++j) unsafeAtomicAdd(orow + j, msg[j]);
}

// ---------------- host ----------------

extern "C" void kernel_launch(void* const* d_in, const int* in_sizes, int n_in,
                              void* d_out, int out_size, void* d_ws, size_t ws_size,
                              hipStream_t stream) {
    const float* node = (const float*)d_in[0];
    const int*   eidx = (const int*)d_in[1];
    const float* sh0  = (const float*)d_in[2];
    const float* sh1  = (const float*)d_in[3];
    const float* sh2  = (const float*)d_in[4];
    const float* W    = (const float*)d_in[5];
    float* out = (float*)d_out;

    const int E = in_sizes[2];          // sh0 has E elements
    const int N = in_sizes[0] / 32;     // node_irreps is [N, 32]
    const int NBUK = (N + NPB - 1) >> NPB_SHIFT;

    // ws layout (words): bcnt[MAXB] | bbase[MAXB+1] | bcursor[MAXB] | (align 64B) payload[E*16]
    size_t int_words = (size_t)MAXB + (MAXB + 1) + MAXB;
    size_t pay_off_w = (int_words + 15) & ~(size_t)15;
    size_t need      = (pay_off_w + (size_t)E * 16) * sizeof(float);

    if (ws_size >= need && NBUK <= MAXB) {
        int* bcnt    = (int*)d_ws;
        int* bbase   = bcnt + MAXB;
        int* bcursor = bbase + (MAXB + 1);
        float* payload = (float*)d_ws + pay_off_w;

        hipMemsetAsync(bcnt, 0, (size_t)NBUK * sizeof(int), stream);

        const int gridE = (E + EPB - 1) / EPB;
        k_bcount<<<gridE, THREADS, 0, stream>>>(eidx + E, bcnt, E, NBUK);
        k_bscan<<<1, 1024, 0, stream>>>(bcnt, bbase, bcursor, NBUK, E);
        k_binsort<<<gridE, THREADS, 0, stream>>>(eidx, bcursor, sh0, sh1, sh2,
                                                 payload, E, NBUK);
        k_aggb<<<NBUK, THREADS, 0, stream>>>(node, payload, bbase, W, out, N);
    } else {
        hipMemsetAsync(d_out, 0, (size_t)out_size * sizeof(float), stream);
        msg_kernel_atomic<<<(E + THREADS - 1) / THREADS, THREADS, 0, stream>>>(
            node, eidx, sh0, sh1, sh2, W, out, E);
    }
}

// Round 9
// 537.780 us; speedup vs baseline: 2.6168x; 2.6168x over previous
//
#include <hip/hip_runtime.h>

#define THREADS 256

typedef float v4f __attribute__((ext_vector_type(4)));

// ---------------- CSR build ----------------

// counts + per-target rank (atomic return value)
__global__ __launch_bounds__(THREADS) void k_hist2(const int* __restrict__ tgt,
                                                   int* __restrict__ cnt,
                                                   int* __restrict__ ke, int E) {
    int e = blockIdx.x * THREADS + threadIdx.x;
    if (e < E) ke[e] = atomicAdd(&cnt[tgt[e]], 1);
}

__global__ __launch_bounds__(THREADS) void k_scan_partial(const int* __restrict__ cnt,
                                                          int* __restrict__ bsum, int N) {
    __shared__ int lds[THREADS];
    int base = blockIdx.x * 1024 + threadIdx.x * 4;
    int s = 0;
    #pragma unroll
    for (int k = 0; k < 4; ++k) { int i = base + k; if (i < N) s += cnt[i]; }
    lds[threadIdx.x] = s; __syncthreads();
    for (int off = THREADS / 2; off > 0; off >>= 1) {
        if (threadIdx.x < off) lds[threadIdx.x] += lds[threadIdx.x + off];
        __syncthreads();
    }
    if (threadIdx.x == 0) bsum[blockIdx.x] = lds[0];
}

__global__ __launch_bounds__(1024) void k_scan_bsum(int* __restrict__ bsum, int NB) {
    __shared__ int lds[1024];
    int t = threadIdx.x;
    int v = (t < NB) ? bsum[t] : 0;
    lds[t] = v; __syncthreads();
    for (int off = 1; off < 1024; off <<= 1) {
        int x = (t >= off) ? lds[t - off] : 0;
        __syncthreads();
        lds[t] += x;
        __syncthreads();
    }
    if (t < NB) bsum[t] = lds[t] - v;   // exclusive
}

__global__ __launch_bounds__(THREADS) void k_scan_final(const int* __restrict__ cnt,
                                                        const int* __restrict__ bsum,
                                                        int* __restrict__ rowptr,
                                                        int N, int E) {
    __shared__ int lds[THREADS];
    int base = blockIdx.x * 1024 + threadIdx.x * 4;
    int v[4]; int local = 0;
    #pragma unroll
    for (int k = 0; k < 4; ++k) {
        int i = base + k;
        v[k] = (i < N) ? cnt[i] : 0;
        local += v[k];
    }
    lds[threadIdx.x] = local; __syncthreads();
    for (int off = 1; off < THREADS; off <<= 1) {
        int x = (threadIdx.x >= off) ? lds[threadIdx.x - off] : 0;
        __syncthreads();
        lds[threadIdx.x] += x;
        __syncthreads();
    }
    int p = lds[threadIdx.x] - local + bsum[blockIdx.x];
    #pragma unroll
    for (int k = 0; k < 4; ++k) {
        int i = base + k;
        if (i < N) { rowptr[i] = p; p += v[k]; }
    }
    if (blockIdx.x == 0 && threadIdx.x == 0) rowptr[N] = E;
}

// ---------------- scatter edge payloads into CSR order (full 64B rows, nt) ----------------
// payload row (16 floats, 64B): [s,u0,u1,u2 | q0,q1,q2,q3 | q4, src(bits), 0,0 | 0,0,0,0]

__global__ __launch_bounds__(THREADS) void k_scatter(const int* __restrict__ eidx,
                                                     const int* __restrict__ ke,
                                                     const int* __restrict__ rowptr,
                                                     const float* __restrict__ sh0,
                                                     const float* __restrict__ sh1,
                                                     const float* __restrict__ sh2,
                                                     float* __restrict__ payload,
                                                     int E) {
    int e = blockIdx.x * THREADS + threadIdx.x;
    if (e >= E) return;
    int src = eidx[e];
    int tgt = eidx[E + e];
    int pos = rowptr[tgt] + ke[e];

    v4f p0 = { sh0[e], sh1[3*e+0], sh1[3*e+1], sh1[3*e+2] };
    v4f p1 = { sh2[5*e+0], sh2[5*e+1], sh2[5*e+2], sh2[5*e+3] };
    v4f p2 = { sh2[5*e+4], __int_as_float(src), 0.f, 0.f };
    v4f p3 = { 0.f, 0.f, 0.f, 0.f };

    v4f* pr = (v4f*)(payload + (size_t)pos * 16);
    __builtin_nontemporal_store(p0, pr + 0);
    __builtin_nontemporal_store(p1, pr + 1);
    __builtin_nontemporal_store(p2, pr + 2);
    __builtin_nontemporal_store(p3, pr + 3);   // full 64B line, single touch
}

// ---------------- fused aggregation in pre-W space + per-node postmix ----------------
// 8 threads per node; thread i = input channel i. 32 nodes per block.

#define ACC_STRIDE 15   // 14 used +1 pad to break LDS bank conflicts

__global__ __launch_bounds__(THREADS) void k_agg2(const float* __restrict__ node,
                                                  const int*   __restrict__ rowptr,
                                                  const float* __restrict__ payload,
                                                  const float* __restrict__ W,
                                                  float*       __restrict__ out, int N) {
    __shared__ float sW[384];
    __shared__ float sAcc[32 * 8 * ACC_STRIDE];
    for (int t = threadIdx.x; t < 384; t += THREADS) sW[t] = W[t];
    __syncthreads();

    constexpr float IS3  = 0.57735026918962576f;
    constexpr float IS6  = 0.40824829046386302f;
    constexpr float IS10 = 0.31622776601683794f;
    constexpr float IS30 = 0.18257418583505536f;

    const int nodeSlot = threadIdx.x >> 3;
    const int i        = threadIdx.x & 7;
    const int n        = blockIdx.x * 32 + nodeSlot;

    float a[14];
    #pragma unroll
    for (int k = 0; k < 14; ++k) a[k] = 0.f;

    if (n < N) {
        const int jbeg = rowptr[n];
        const int jend = rowptr[n + 1];

        if (jbeg < jend) {
            // software pipeline: payload[j+1] loads while node-row[j] is in flight
            const v4f* pr = (const v4f*)(payload + (size_t)jbeg * 16);
            v4f c0 = __builtin_nontemporal_load(pr + 0);
            v4f c1 = __builtin_nontemporal_load(pr + 1);
            v4f c2 = __builtin_nontemporal_load(pr + 2);

            for (int j = jbeg; j < jend; ++j) {
                v4f n0, n1, n2;
                if (j + 1 < jend) {
                    const v4f* prn = (const v4f*)(payload + (size_t)(j + 1) * 16);
                    n0 = __builtin_nontemporal_load(prn + 0);
                    n1 = __builtin_nontemporal_load(prn + 1);
                    n2 = __builtin_nontemporal_load(prn + 2);
                }

                const int src = __float_as_int(c2.y);
                const float* nr = node + (size_t)src * 32;
                const float f0 = nr[i];
                const float x  = nr[8 + 3*i + 0];
                const float y  = nr[8 + 3*i + 1];
                const float z  = nr[8 + 3*i + 2];

                const float s  = c0.x, u0 = c0.y, u1 = c0.z, u2 = c0.w;
                const float q0 = c1.x, q1 = c1.y, q2 = c1.z, q3 = c1.w, q4 = c2.x;

                const float Q00 = -q2*IS30 - q4*IS10;
                const float Q01 =  q1*IS10;
                const float Q02 =  q0*IS10;
                const float Q11 =  2.0f*q2*IS30;
                const float Q12 =  q3*IS10;
                const float Q22 = -q2*IS30 + q4*IS10;

                a[0]  += s * f0;                       // c0
                a[1]  += u0*x + u1*y + u2*z;           // c3 (pre IS3)
                a[2]  += s * x;                        // c1 (pre IS3)
                a[3]  += s * y;
                a[4]  += s * z;
                a[5]  += f0 * u0;                      // c2 (pre IS3)
                a[6]  += f0 * u1;
                a[7]  += f0 * u2;
                a[8]  += u1*z - u2*y;                  // c4 (pre IS6)
                a[9]  += u2*x - u0*z;
                a[10] += u0*y - u1*x;
                a[11] += Q00*x + Q01*y + Q02*z;        // c5
                a[12] += Q01*x + Q11*y + Q12*z;
                a[13] += Q02*x + Q12*y + Q22*z;

                c0 = n0; c1 = n1; c2 = n2;
            }
        }
    }

    // fold norms (linear, once per node)
    #pragma unroll
    for (int k = 1; k < 8; ++k) a[k] *= IS3;
    #pragma unroll
    for (int k = 8; k < 11; ++k) a[k] *= IS6;

    float* myAcc = &sAcc[(nodeSlot * 8 + i) * ACC_STRIDE];
    #pragma unroll
    for (int k = 0; k < 14; ++k) myAcc[k] = a[k];
    __syncthreads();

    if (n < N) {
        const int o = i;
        float o0 = 0.f, ox = 0.f, oy = 0.f, oz = 0.f;
        #pragma unroll
        for (int ii = 0; ii < 8; ++ii) {
            const float* A = &sAcc[(nodeSlot * 8 + ii) * ACC_STRIDE];
            const float w0 = sW[  0 + ii*8 + o];
            const float w1 = sW[ 64 + ii*8 + o];
            const float w2 = sW[128 + ii*8 + o];
            const float w3 = sW[192 + ii*8 + o];
            const float w4 = sW[256 + ii*8 + o];
            const float w5 = sW[320 + ii*8 + o];
            o0 += w0*A[0]  + w3*A[1];
            ox += w1*A[2]  + w2*A[5] + w4*A[8]  + w5*A[11];
            oy += w1*A[3]  + w2*A[6] + w4*A[9]  + w5*A[12];
            oz += w1*A[4]  + w2*A[7] + w4*A[10] + w5*A[13];
        }
        float* orow = out + (size_t)n * 32;
        orow[o]         = o0;
        orow[8 + 3*o+0] = ox;
        orow[8 + 3*o+1] = oy;
        orow[8 + 3*o+2] = oz;
    }
}

// ---------------- fallback: round-1 atomic kernel ----------------

__global__ __launch_bounds__(THREADS) void msg_kernel_atomic(
    const float* __restrict__ node,
    const int*   __restrict__ eidx,
    const float* __restrict__ sh0,
    const float* __restrict__ sh1,
    const float* __restrict__ sh2,
    const float* __restrict__ W,
    float*       __restrict__ out,
    int E)
{
    __shared__ float sW[384];
    for (int t = threadIdx.x; t < 384; t += THREADS) sW[t] = W[t];
    __syncthreads();

    int e = blockIdx.x * THREADS + threadIdx.x;
    if (e >= E) return;

    constexpr float IS3  = 0.57735026918962576f;
    constexpr float IS6  = 0.40824829046386302f;
    constexpr float IS10 = 0.31622776601683794f;
    constexpr float IS30 = 0.18257418583505536f;

    const int src = eidx[e];
    const int tgt = eidx[E + e];

    const float s  = sh0[e];
    const float u0 = sh1[3*e+0], u1 = sh1[3*e+1], u2 = sh1[3*e+2];
    const float q0 = sh2[5*e+0], q1 = sh2[5*e+1], q2 = sh2[5*e+2],
                q3 = sh2[5*e+3], q4 = sh2[5*e+4];

    const float Q00 = -q2*IS30 - q4*IS10;
    const float Q01 =  q1*IS10;
    const float Q02 =  q0*IS10;
    const float Q11 =  2.0f*q2*IS30;
    const float Q12 =  q3*IS10;
    const float Q22 = -q2*IS30 + q4*IS10;

    float f[32];
    {
        const float4* nr = (const float4*)(node + (size_t)src * 32);
        #pragma unroll
        for (int i = 0; i < 8; ++i) {
            float4 v = nr[i];
            f[4*i+0]=v.x; f[4*i+1]=v.y; f[4*i+2]=v.z; f[4*i+3]=v.w;
        }
    }

    float msg[32];
    #pragma unroll
    for (int j = 0; j < 32; ++j) msg[j] = 0.0f;

    const float s13 = s * IS3;

    #pragma unroll
    for (int i = 0; i < 8; ++i) {
        const float f0i = f[i];
        const float x = f[8+3*i+0], y = f[8+3*i+1], z = f[8+3*i+2];
        const float c0  = s * f0i;
        const float c3  = IS3 * (u0*x + u1*y + u2*z);
        const float p2  = IS3 * f0i;
        const float c1x = s13*x, c1y = s13*y, c1z = s13*z;
        const float c2x = p2*u0, c2y = p2*u1, c2z = p2*u2;
        const float c4x = IS6*(u1*z - u2*y);
        const float c4y = IS6*(u2*x - u0*z);
        const float c4z = IS6*(u0*y - u1*x);
        const float c5x = Q00*x + Q01*y + Q02*z;
        const float c5y = Q01*x + Q11*y + Q12*z;
        const float c5z = Q02*x + Q12*y + Q22*z;

        float wr[6][8];
        #pragma unroll
        for (int c = 0; c < 6; ++c) {
            float4 aa = *(const float4*)&sW[c*64 + i*8 + 0];
            float4 bb = *(const float4*)&sW[c*64 + i*8 + 4];
            wr[c][0]=aa.x; wr[c][1]=aa.y; wr[c][2]=aa.z; wr[c][3]=aa.w;
            wr[c][4]=bb.x; wr[c][5]=bb.y; wr[c][6]=bb.z; wr[c][7]=bb.w;
        }

        #pragma unroll
        for (int o = 0; o < 8; ++o) {
            msg[o] += wr[0][o]*c0 + wr[3][o]*c3;
            msg[8+3*o+0] += wr[1][o]*c1x + wr[2][o]*c2x + wr[4][o]*c4x + wr[5][o]*c5x;
            msg[8+3*o+1] += wr[1][o]*c1y + wr[2][o]*c2y + wr[4][o]*c4y + wr[5][o]*c5y;
            msg[8+3*o+2] += wr[1][o]*c1z + wr[2][o]*c2z + wr[4][o]*c4z + wr[5][o]*c5z;
        }
    }

    float* orow = out + (size_t)tgt * 32;
    #pragma unroll
    for (int j = 0; j < 32; ++j) unsafeAtomicAdd(orow + j, msg[j]);
}

// ---------------- host ----------------

extern "C" void kernel_launch(void* const* d_in, const int* in_sizes, int n_in,
                              void* d_out, int out_size, void* d_ws, size_t ws_size,
                              hipStream_t stream) {
    const float* node = (const float*)d_in[0];
    const int*   eidx = (const int*)d_in[1];
    const float* sh0  = (const float*)d_in[2];
    const float* sh1  = (const float*)d_in[3];
    const float* sh2  = (const float*)d_in[4];
    const float* W    = (const float*)d_in[5];
    float* out = (float*)d_out;

    const int E = in_sizes[2];          // sh0 has E elements
    const int N = in_sizes[0] / 32;     // node_irreps is [N, 32]
    const int NB = (N + 1023) / 1024;

    // ws layout (words): rowptr[N+1] | cnt[N] | bsum[1024] | ke[E] | (align 64B) payload[E*16]
    size_t int_words = (size_t)(N + 1) + N + 1024 + (size_t)E;
    size_t pay_off_w = (int_words + 15) & ~(size_t)15;       // 64B-align payload
    size_t need      = (pay_off_w + (size_t)E * 16) * sizeof(float);

    if (ws_size >= need && NB <= 1024) {
        int* rowptr = (int*)d_ws;
        int* cnt    = rowptr + (N + 1);
        int* bsum   = cnt + N;
        int* ke     = bsum + 1024;
        float* payload = (float*)d_ws + pay_off_w;

        hipMemsetAsync(cnt, 0, (size_t)N * sizeof(int), stream);

        k_hist2<<<(E + THREADS - 1) / THREADS, THREADS, 0, stream>>>(eidx + E, cnt, ke, E);
        k_scan_partial<<<NB, THREADS, 0, stream>>>(cnt, bsum, N);
        k_scan_bsum<<<1, 1024, 0, stream>>>(bsum, NB);
        k_scan_final<<<NB, THREADS, 0, stream>>>(cnt, bsum, rowptr, N, E);
        k_scatter<<<(E + THREADS - 1) / THREADS, THREADS, 0, stream>>>(
            eidx, ke, rowptr, sh0, sh1, sh2, payload, E);

        k_agg2<<<(N + 31) / 32, THREADS, 0, stream>>>(node, rowptr, payload, W, out, N);
    } else {
        hipMemsetAsync(d_out, 0, (size_t)out_size * sizeof(float), stream);
        msg_kernel_atomic<<<(E + THREADS - 1) / THREADS, THREADS, 0, stream>>>(
            node, eidx, sh0, sh1, sh2, W, out, E);
    }
}

// Round 10
// 347.477 us; speedup vs baseline: 4.0499x; 1.5477x over previous
//
#include <hip/hip_runtime.h>

#define THREADS 256

typedef float v4f __attribute__((ext_vector_type(4)));

// ---------------- CSR build ----------------

// counts + per-target rank (atomic return value)
__global__ __launch_bounds__(THREADS) void k_hist2(const int* __restrict__ tgt,
                                                   int* __restrict__ cnt,
                                                   int* __restrict__ ke, int E) {
    int e = blockIdx.x * THREADS + threadIdx.x;
    if (e < E) ke[e] = atomicAdd(&cnt[tgt[e]], 1);
}

__global__ __launch_bounds__(THREADS) void k_scan_partial(const int* __restrict__ cnt,
                                                          int* __restrict__ bsum, int N) {
    __shared__ int lds[THREADS];
    int base = blockIdx.x * 1024 + threadIdx.x * 4;
    int s = 0;
    #pragma unroll
    for (int k = 0; k < 4; ++k) { int i = base + k; if (i < N) s += cnt[i]; }
    lds[threadIdx.x] = s; __syncthreads();
    for (int off = THREADS / 2; off > 0; off >>= 1) {
        if (threadIdx.x < off) lds[threadIdx.x] += lds[threadIdx.x + off];
        __syncthreads();
    }
    if (threadIdx.x == 0) bsum[blockIdx.x] = lds[0];
}

__global__ __launch_bounds__(1024) void k_scan_bsum(int* __restrict__ bsum, int NB) {
    __shared__ int lds[1024];
    int t = threadIdx.x;
    int v = (t < NB) ? bsum[t] : 0;
    lds[t] = v; __syncthreads();
    for (int off = 1; off < 1024; off <<= 1) {
        int x = (t >= off) ? lds[t - off] : 0;
        __syncthreads();
        lds[t] += x;
        __syncthreads();
    }
    if (t < NB) bsum[t] = lds[t] - v;   // exclusive
}

__global__ __launch_bounds__(THREADS) void k_scan_final(const int* __restrict__ cnt,
                                                        const int* __restrict__ bsum,
                                                        int* __restrict__ rowptr,
                                                        int N, int E) {
    __shared__ int lds[THREADS];
    int base = blockIdx.x * 1024 + threadIdx.x * 4;
    int v[4]; int local = 0;
    #pragma unroll
    for (int k = 0; k < 4; ++k) {
        int i = base + k;
        v[k] = (i < N) ? cnt[i] : 0;
        local += v[k];
    }
    lds[threadIdx.x] = local; __syncthreads();
    for (int off = 1; off < THREADS; off <<= 1) {
        int x = (threadIdx.x >= off) ? lds[threadIdx.x - off] : 0;
        __syncthreads();
        lds[threadIdx.x] += x;
        __syncthreads();
    }
    int p = lds[threadIdx.x] - local + bsum[blockIdx.x];
    #pragma unroll
    for (int k = 0; k < 4; ++k) {
        int i = base + k;
        if (i < N) { rowptr[i] = p; p += v[k]; }
    }
    if (blockIdx.x == 0 && threadIdx.x == 0) rowptr[N] = E;
}

// ---------------- scatter edge payloads into CSR order (full 64B rows) ----------------
// payload row (16 floats, 64B): [s,u0,u1,u2 | q0,q1,q2,q3 | q4, src(bits), 0,0 | 0,0,0,0]
// Plain stores: the L2 merges the 4 consecutive 16B stores into ONE line writeback.
// (r9 measured: nontemporal stores here bypass the merge -> 2.4x write traffic, 3x time.)

__global__ __launch_bounds__(THREADS) void k_scatter(const int* __restrict__ eidx,
                                                     const int* __restrict__ ke,
                                                     const int* __restrict__ rowptr,
                                                     const float* __restrict__ sh0,
                                                     const float* __restrict__ sh1,
                                                     const float* __restrict__ sh2,
                                                     float* __restrict__ payload,
                                                     int E) {
    int e = blockIdx.x * THREADS + threadIdx.x;
    if (e >= E) return;
    int src = eidx[e];
    int tgt = eidx[E + e];
    int pos = rowptr[tgt] + ke[e];

    float4 p0 = make_float4(sh0[e], sh1[3*e+0], sh1[3*e+1], sh1[3*e+2]);
    float4 p1 = make_float4(sh2[5*e+0], sh2[5*e+1], sh2[5*e+2], sh2[5*e+3]);
    float4 p2 = make_float4(sh2[5*e+4], __int_as_float(src), 0.f, 0.f);
    float4 p3 = make_float4(0.f, 0.f, 0.f, 0.f);

    float4* pr = (float4*)(payload + (size_t)pos * 16);
    pr[0] = p0; pr[1] = p1; pr[2] = p2; pr[3] = p3;   // full 64B line, one touch
}

// ---------------- fused aggregation in pre-W space + per-node postmix ----------------
// 8 threads per node; thread i = input channel i. 32 nodes per block.

#define ACC_STRIDE 15   // 14 used +1 pad to break LDS bank conflicts

__global__ __launch_bounds__(THREADS) void k_agg2(const float* __restrict__ node,
                                                  const int*   __restrict__ rowptr,
                                                  const float* __restrict__ payload,
                                                  const float* __restrict__ W,
                                                  float*       __restrict__ out, int N) {
    __shared__ float sW[384];
    __shared__ float sAcc[32 * 8 * ACC_STRIDE];
    for (int t = threadIdx.x; t < 384; t += THREADS) sW[t] = W[t];
    __syncthreads();

    constexpr float IS3  = 0.57735026918962576f;
    constexpr float IS6  = 0.40824829046386302f;
    constexpr float IS10 = 0.31622776601683794f;
    constexpr float IS30 = 0.18257418583505536f;

    const int nodeSlot = threadIdx.x >> 3;
    const int i        = threadIdx.x & 7;
    const int n        = blockIdx.x * 32 + nodeSlot;

    float a[14];
    #pragma unroll
    for (int k = 0; k < 14; ++k) a[k] = 0.f;

    if (n < N) {
        const int jbeg = rowptr[n];
        const int jend = rowptr[n + 1];

        if (jbeg < jend) {
            // software pipeline: payload[j+1] (nt: zero-reuse stream, spare L2 for node table)
            const v4f* pr = (const v4f*)(payload + (size_t)jbeg * 16);
            v4f c0 = __builtin_nontemporal_load(pr + 0);
            v4f c1 = __builtin_nontemporal_load(pr + 1);
            v4f c2 = __builtin_nontemporal_load(pr + 2);

            for (int j = jbeg; j < jend; ++j) {
                v4f n0, n1, n2;
                if (j + 1 < jend) {
                    const v4f* prn = (const v4f*)(payload + (size_t)(j + 1) * 16);
                    n0 = __builtin_nontemporal_load(prn + 0);
                    n1 = __builtin_nontemporal_load(prn + 1);
                    n2 = __builtin_nontemporal_load(prn + 2);
                }

                const int src = __float_as_int(c2.y);
                const float* nr = node + (size_t)src * 32;
                const float f0 = nr[i];
                const float x  = nr[8 + 3*i + 0];
                const float y  = nr[8 + 3*i + 1];
                const float z  = nr[8 + 3*i + 2];

                const float s  = c0.x, u0 = c0.y, u1 = c0.z, u2 = c0.w;
                const float q0 = c1.x, q1 = c1.y, q2 = c1.z, q3 = c1.w, q4 = c2.x;

                const float Q00 = -q2*IS30 - q4*IS10;
                const float Q01 =  q1*IS10;
                const float Q02 =  q0*IS10;
                const float Q11 =  2.0f*q2*IS30;
                const float Q12 =  q3*IS10;
                const float Q22 = -q2*IS30 + q4*IS10;

                a[0]  += s * f0;                       // c0
                a[1]  += u0*x + u1*y + u2*z;           // c3 (pre IS3)
                a[2]  += s * x;                        // c1 (pre IS3)
                a[3]  += s * y;
                a[4]  += s * z;
                a[5]  += f0 * u0;                      // c2 (pre IS3)
                a[6]  += f0 * u1;
                a[7]  += f0 * u2;
                a[8]  += u1*z - u2*y;                  // c4 (pre IS6)
                a[9]  += u2*x - u0*z;
                a[10] += u0*y - u1*x;
                a[11] += Q00*x + Q01*y + Q02*z;        // c5
                a[12] += Q01*x + Q11*y + Q12*z;
                a[13] += Q02*x + Q12*y + Q22*z;

                c0 = n0; c1 = n1; c2 = n2;
            }
        }
    }

    // fold norms (linear, once per node)
    #pragma unroll
    for (int k = 1; k < 8; ++k) a[k] *= IS3;
    #pragma unroll
    for (int k = 8; k < 11; ++k) a[k] *= IS6;

    float* myAcc = &sAcc[(nodeSlot * 8 + i) * ACC_STRIDE];
    #pragma unroll
    for (int k = 0; k < 14; ++k) myAcc[k] = a[k];
    __syncthreads();

    if (n < N) {
        const int o = i;
        float o0 = 0.f, ox = 0.f, oy = 0.f, oz = 0.f;
        #pragma unroll
        for (int ii = 0; ii < 8; ++ii) {
            const float* A = &sAcc[(nodeSlot * 8 + ii) * ACC_STRIDE];
            const float w0 = sW[  0 + ii*8 + o];
            const float w1 = sW[ 64 + ii*8 + o];
            const float w2 = sW[128 + ii*8 + o];
            const float w3 = sW[192 + ii*8 + o];
            const float w4 = sW[256 + ii*8 + o];
            const float w5 = sW[320 + ii*8 + o];
            o0 += w0*A[0]  + w3*A[1];
            ox += w1*A[2]  + w2*A[5] + w4*A[8]  + w5*A[11];
            oy += w1*A[3]  + w2*A[6] + w4*A[9]  + w5*A[12];
            oz += w1*A[4]  + w2*A[7] + w4*A[10] + w5*A[13];
        }
        float* orow = out + (size_t)n * 32;
        orow[o]         = o0;
        orow[8 + 3*o+0] = ox;
        orow[8 + 3*o+1] = oy;
        orow[8 + 3*o+2] = oz;
    }
}

// ---------------- fallback: round-1 atomic kernel ----------------

__global__ __launch_bounds__(THREADS) void msg_kernel_atomic(
    const float* __restrict__ node,
    const int*   __restrict__ eidx,
    const float* __restrict__ sh0,
    const float* __restrict__ sh1,
    const float* __restrict__ sh2,
    const float* __restrict__ W,
    float*       __restrict__ out,
    int E)
{
    __shared__ float sW[384];
    for (int t = threadIdx.x; t < 384; t += THREADS) sW[t] = W[t];
    __syncthreads();

    int e = blockIdx.x * THREADS + threadIdx.x;
    if (e >= E) return;

    constexpr float IS3  = 0.57735026918962576f;
    constexpr float IS6  = 0.40824829046386302f;
    constexpr float IS10 = 0.31622776601683794f;
    constexpr float IS30 = 0.18257418583505536f;

    const int src = eidx[e];
    const int tgt = eidx[E + e];

    const float s  = sh0[e];
    const float u0 = sh1[3*e+0], u1 = sh1[3*e+1], u2 = sh1[3*e+2];
    const float q0 = sh2[5*e+0], q1 = sh2[5*e+1], q2 = sh2[5*e+2],
                q3 = sh2[5*e+3], q4 = sh2[5*e+4];

    const float Q00 = -q2*IS30 - q4*IS10;
    const float Q01 =  q1*IS10;
    const float Q02 =  q0*IS10;
    const float Q11 =  2.0f*q2*IS30;
    const float Q12 =  q3*IS10;
    const float Q22 = -q2*IS30 + q4*IS10;

    float f[32];
    {
        const float4* nr = (const float4*)(node + (size_t)src * 32);
        #pragma unroll
        for (int i = 0; i < 8; ++i) {
            float4 v = nr[i];
            f[4*i+0]=v.x; f[4*i+1]=v.y; f[4*i+2]=v.z; f[4*i+3]=v.w;
        }
    }

    float msg[32];
    #pragma unroll
    for (int j = 0; j < 32; ++j) msg[j] = 0.0f;

    const float s13 = s * IS3;

    #pragma unroll
    for (int i = 0; i < 8; ++i) {
        const float f0i = f[i];
        const float x = f[8+3*i+0], y = f[8+3*i+1], z = f[8+3*i+2];
        const float c0  = s * f0i;
        const float c3  = IS3 * (u0*x + u1*y + u2*z);
        const float p2  = IS3 * f0i;
        const float c1x = s13*x, c1y = s13*y, c1z = s13*z;
        const float c2x = p2*u0, c2y = p2*u1, c2z = p2*u2;
        const float c4x = IS6*(u1*z - u2*y);
        const float c4y = IS6*(u2*x - u0*z);
        const float c4z = IS6*(u0*y - u1*x);
        const float c5x = Q00*x + Q01*y + Q02*z;
        const float c5y = Q01*x + Q11*y + Q12*z;
        const float c5z = Q02*x + Q12*y + Q22*z;

        float wr[6][8];
        #pragma unroll
        for (int c = 0; c < 6; ++c) {
            float4 aa = *(const float4*)&sW[c*64 + i*8 + 0];
            float4 bb = *(const float4*)&sW[c*64 + i*8 + 4];
            wr[c][0]=aa.x; wr[c][1]=aa.y; wr[c][2]=aa.z; wr[c][3]=aa.w;
            wr[c][4]=bb.x; wr[c][5]=bb.y; wr[c][6]=bb.z; wr[c][7]=bb.w;
        }

        #pragma unroll
        for (int o = 0; o < 8; ++o) {
            msg[o] += wr[0][o]*c0 + wr[3][o]*c3;
            msg[8+3*o+0] += wr[1][o]*c1x + wr[2][o]*c2x + wr[4][o]*c4x + wr[5][o]*c5x;
            msg[8+3*o+1] += wr[1][o]*c1y + wr[2][o]*c2y + wr[4][o]*c4y + wr[5][o]*c5y;
            msg[8+3*o+2] += wr[1][o]*c1z + wr[2][o]*c2z + wr[4][o]*c4z + wr[5][o]*c5z;
        }
    }

    float* orow = out + (size_t)tgt * 32;
    #pragma unroll
    for (int j = 0; j < 32; ++j) unsafeAtomicAdd(orow + j, msg[j]);
}

// ---------------- host ----------------

extern "C" void kernel_launch(void* const* d_in, const int* in_sizes, int n_in,
                              void* d_out, int out_size, void* d_ws, size_t ws_size,
                              hipStream_t stream) {
    const float* node = (const float*)d_in[0];
    const int*   eidx = (const int*)d_in[1];
    const float* sh0  = (const float*)d_in[2];
    const float* sh1  = (const float*)d_in[3];
    const float* sh2  = (const float*)d_in[4];
    const float* W    = (const float*)d_in[5];
    float* out = (float*)d_out;

    const int E = in_sizes[2];          // sh0 has E elements
    const int N = in_sizes[0] / 32;     // node_irreps is [N, 32]
    const int NB = (N + 1023) / 1024;

    // ws layout (words): rowptr[N+1] | cnt[N] | bsum[1024] | ke[E] | (align 64B) payload[E*16]
    size_t int_words = (size_t)(N + 1) + N + 1024 + (size_t)E;
    size_t pay_off_w = (int_words + 15) & ~(size_t)15;       // 64B-align payload
    size_t need      = (pay_off_w + (size_t)E * 16) * sizeof(float);

    if (ws_size >= need && NB <= 1024) {
        int* rowptr = (int*)d_ws;
        int* cnt    = rowptr + (N + 1);
        int* bsum   = cnt + N;
        int* ke     = bsum + 1024;
        float* payload = (float*)d_ws + pay_off_w;

        hipMemsetAsync(cnt, 0, (size_t)N * sizeof(int), stream);

        k_hist2<<<(E + THREADS - 1) / THREADS, THREADS, 0, stream>>>(eidx + E, cnt, ke, E);
        k_scan_partial<<<NB, THREADS, 0, stream>>>(cnt, bsum, N);
        k_scan_bsum<<<1, 1024, 0, stream>>>(bsum, NB);
        k_scan_final<<<NB, THREADS, 0, stream>>>(cnt, bsum, rowptr, N, E);
        k_scatter<<<(E + THREADS - 1) / THREADS, THREADS, 0, stream>>>(
            eidx, ke, rowptr, sh0, sh1, sh2, payload, E);

        k_agg2<<<(N + 31) / 32, THREADS, 0, stream>>>(node, rowptr, payload, W, out, N);
    } else {
        hipMemsetAsync(d_out, 0, (size_t)out_size * sizeof(float), stream);
        msg_kernel_atomic<<<(E + THREADS - 1) / THREADS, THREADS, 0, stream>>>(
            node, eidx, sh0, sh1, sh2, W, out, E);
    }
}